// Round 8
// baseline (727.127 us; speedup 1.0000x reference)
//
#include <hip/hip_runtime.h>

// GIN_MLP: 2x GIN conv (N=100000, E=1.6M, H=128) + per-batch context MLP (B=4096).
// Device-built dst-CSR (rank-based atomic-free scatter, 8-aligned padded rows)
// -> fused aggregate+GEMM -> tiled per-batch MLP. All f32.
// R8: (1) stage-1 gathers are WAVE-scoped with scalarized addressing: edge
// descriptors are wave-uniform, src/w go to SGPRs via readfirstlane, gather is
// global_load_dwordx2 with constant voffset (lane*8) -- zero per-edge VALU
// address math; flush writes standard LDS layout (f=lane*2), de-permute gone.
// (2) final_kernel tiles 16 batch elements per block: Wc1 traffic 800->50 MB.

#define CONV_NPB 32

__global__ void prep_transpose(const float* __restrict__ W1, const float* __restrict__ W2,
                               const float* __restrict__ Wc1, const float* __restrict__ Wc2,
                               float* __restrict__ Wt1, float* __restrict__ Wt2,
                               float* __restrict__ Wc1t, float* __restrict__ Wc2t) {
  int i = blockIdx.x * blockDim.x + threadIdx.x;
  if (i < 16384) {
    int f = i >> 7, k = i & 127;
    Wt1[k * 128 + f] = W1[i];
  } else if (i < 32768) {
    int j = i - 16384; int f = j >> 7, k = j & 127;
    Wt2[k * 128 + f] = W2[j];
  } else if (i < 81920) {
    int j = i - 32768; int f = j / 384, k = j % 384;
    Wc1t[k * 128 + f] = Wc1[j];
  } else if (i < 90112) {
    int j = i - 81920; int f = j >> 7, k = j & 127;
    Wc2t[k * 64 + f] = Wc2[j];
  }
}

// counts per-dst degree AND records each edge's arrival rank (makes scatter atomic-free)
__global__ void hist_kernel(const int* __restrict__ dst, int* __restrict__ cnt,
                            int* __restrict__ rank, int E) {
  int e = blockIdx.x * blockDim.x + threadIdx.x;
  if (e < E) rank[e] = atomicAdd(&cnt[dst[e]], 1);
}

// per-2048-chunk exclusive scan of PADDED counts (ceil(cnt/8)*8); bsum[b] = chunk total
__global__ void scan1_kernel(const int* __restrict__ cnt, int* __restrict__ prow,
                             int* __restrict__ bsum, int n) {
  __shared__ int smem[256];
  const int t = threadIdx.x;
  const int base = blockIdx.x * 2048 + t * 8;
  int v[8];
  int s = 0;
#pragma unroll
  for (int j = 0; j < 8; ++j) {
    int idx = base + j;
    v[j] = (idx < n) ? ((cnt[idx] + 7) & ~7) : 0;
    s += v[j];
  }
  smem[t] = s;
  __syncthreads();
  for (int off = 1; off < 256; off <<= 1) {
    int add = (t >= off) ? smem[t - off] : 0;
    __syncthreads();
    smem[t] += add;
    __syncthreads();
  }
  int run = smem[t] - s;
  if (t == 255) bsum[blockIdx.x] = smem[255];
#pragma unroll
  for (int j = 0; j < 8; ++j) {
    int idx = base + j;
    if (idx < n) prow[idx] = run;
    run += v[j];
  }
}

// 64-lane shuffle scan (nchunk=49 fits); also appends grand total at bsum[nb]
__global__ void scan2_kernel(int* __restrict__ bsum, int nb) {
  const int t = threadIdx.x;
  if (nb <= 64) {
    const int orig = (t < nb) ? bsum[t] : 0;
    int v = orig;
#pragma unroll
    for (int off = 1; off < 64; off <<= 1) {
      int u = __shfl_up(v, off);
      if (t >= off) v += u;
    }
    if (t == nb - 1) bsum[nb] = v;
    if (t < nb) bsum[t] = v - orig;
  } else if (t == 0) {
    int run = 0;
    for (int i = 0; i < nb; ++i) { int v = bsum[i]; bsum[i] = run; run += v; }
    bsum[nb] = run;
  }
}

__global__ void scan3_kernel(int* __restrict__ prow, const int* __restrict__ bsum,
                             int n, int nchunk) {
  int i = blockIdx.x * blockDim.x + threadIdx.x;
  if (i < n) prow[i] += bsum[i >> 11];
  if (i == 0) prow[n] = bsum[nchunk];
}

// atomic-free scatter into padded CSR (epack pre-zeroed -> pad slots contribute 0)
__global__ void scatter_kernel(const int* __restrict__ src, const int* __restrict__ dst,
                               const float* __restrict__ w, const int* __restrict__ prow,
                               const int* __restrict__ rank, int2* __restrict__ epack, int E) {
  int e = blockIdx.x * blockDim.x + threadIdx.x;
  if (e < E) {
    int pos = prow[dst[e]] + rank[e];
    epack[pos] = make_int2(src[e], __float_as_int(w[e]));
  }
}

// Stage 1: block's 32 rows = contiguous 8-aligned padded edge range split into
// 4 WAVE chunks (multiples of 8). Per 8-edge batch: 4 wave-uniform int4
// descriptor loads, 8 src/w -> SGPR via readfirstlane, 8 independent
// global_load_dwordx2 gathers (scalar base + constant lane*8 voffset: no VALU
// addressing), 16 FMA (SGPR weight operand). Flush to standard-layout LDS
// (f = lane*2) only at row transitions. Stage 2: (1+eps)x + agg/deg.
// Stage 3: 32x128 @ 128x128 f32 GEMM.
__launch_bounds__(256, 8)
__global__ void conv_kernel(const float* __restrict__ xin, float* __restrict__ xout,
                            const int* __restrict__ prow, const int* __restrict__ cnt,
                            const int2* __restrict__ epack,
                            const float* __restrict__ Wt,
                            const float* __restrict__ bias, const float* __restrict__ eps,
                            int epsidx, int dorelu, int zerorow0, int n) {
  __shared__ float xm[CONV_NPB * 128];
  __shared__ int rp_s[CONV_NPB + 1];
  const int t = threadIdx.x;
  const int nb = blockIdx.x * CONV_NPB;
  const float epsv = 1.0f + eps[epsidx];

  // zero accumulator tile + cache padded rowptr slice
#pragma unroll
  for (int i = 0; i < 4; ++i)
    *(float4*)&xm[(t + i * 256) * 4] = make_float4(0.f, 0.f, 0.f, 0.f);
  if (t <= CONV_NPB) {
    int node = nb + t;
    rp_s[t] = prow[node <= n ? node : n];
  }
  __syncthreads();

  // ---- stage 1: wave-scoped scalar-addressed gather ----
  {
    const int wvid = t >> 6;       // wave 0..3
    const int lane = t & 63;
    const int f0 = lane * 2;
    const int e0 = rp_s[0], eT = rp_s[CONV_NPB];
    const int nbat = (eT - e0) >> 3;
    const int chunk = ((nbat + 3) >> 2) << 3;    // edges per wave, mult of 8
    const int jb = e0 + wvid * chunk;
    const int je = min(jb + chunk, eT);
    if (jb < je) {
      const int4* ep4 = (const int4*)epack;      // (src0,w0,src1,w1)
      int r = 0;
      while (rp_s[r + 1] <= jb) ++r;
      float ax = 0.f, ay = 0.f;
      for (int j = jb; j < je; j += 8) {
        if (rp_s[r + 1] <= j) {                  // row transition: flush
          atomicAdd(&xm[r * 128 + f0], ax);
          atomicAdd(&xm[r * 128 + f0 + 1], ay);
          ax = 0.f; ay = 0.f;
          do { ++r; } while (rp_s[r + 1] <= j);
        }
        const int h = j >> 1;
        const int4 q0 = ep4[h + 0];
        const int4 q1 = ep4[h + 1];
        const int4 q2 = ep4[h + 2];
        const int4 q3 = ep4[h + 3];
        const int s0 = __builtin_amdgcn_readfirstlane(q0.x);
        const int s1 = __builtin_amdgcn_readfirstlane(q0.z);
        const int s2 = __builtin_amdgcn_readfirstlane(q1.x);
        const int s3 = __builtin_amdgcn_readfirstlane(q1.z);
        const int s4 = __builtin_amdgcn_readfirstlane(q2.x);
        const int s5 = __builtin_amdgcn_readfirstlane(q2.z);
        const int s6 = __builtin_amdgcn_readfirstlane(q3.x);
        const int s7 = __builtin_amdgcn_readfirstlane(q3.z);
        const float2 a0 = *(const float2*)&xin[(size_t)s0 * 128 + f0];
        const float2 a1 = *(const float2*)&xin[(size_t)s1 * 128 + f0];
        const float2 a2 = *(const float2*)&xin[(size_t)s2 * 128 + f0];
        const float2 a3 = *(const float2*)&xin[(size_t)s3 * 128 + f0];
        const float2 a4 = *(const float2*)&xin[(size_t)s4 * 128 + f0];
        const float2 a5 = *(const float2*)&xin[(size_t)s5 * 128 + f0];
        const float2 a6 = *(const float2*)&xin[(size_t)s6 * 128 + f0];
        const float2 a7 = *(const float2*)&xin[(size_t)s7 * 128 + f0];
        const float w0 = __uint_as_float(__builtin_amdgcn_readfirstlane(q0.y));
        const float w1 = __uint_as_float(__builtin_amdgcn_readfirstlane(q0.w));
        const float w2 = __uint_as_float(__builtin_amdgcn_readfirstlane(q1.y));
        const float w3 = __uint_as_float(__builtin_amdgcn_readfirstlane(q1.w));
        const float w4 = __uint_as_float(__builtin_amdgcn_readfirstlane(q2.y));
        const float w5 = __uint_as_float(__builtin_amdgcn_readfirstlane(q2.w));
        const float w6 = __uint_as_float(__builtin_amdgcn_readfirstlane(q3.y));
        const float w7 = __uint_as_float(__builtin_amdgcn_readfirstlane(q3.w));
        ax += w0 * a0.x + w1 * a1.x + w2 * a2.x + w3 * a3.x
            + w4 * a4.x + w5 * a5.x + w6 * a6.x + w7 * a7.x;
        ay += w0 * a0.y + w1 * a1.y + w2 * a2.y + w3 * a3.y
            + w4 * a4.y + w5 * a5.y + w6 * a6.y + w7 * a7.y;
      }
      atomicAdd(&xm[r * 128 + f0], ax);
      atomicAdd(&xm[r * 128 + f0 + 1], ay);
    }
  }
  __syncthreads();

  // ---- stage 2: finalize (1+eps)*x + agg/deg (standard layout, no permute) ----
  {
#pragma unroll
    for (int q = 0; q < 4; ++q) {
      const int task = t + q * 256;             // 32 rows x 32 fgroups
      const int r = task >> 5;
      const int f0 = (task & 31) * 4;
      const int node = nb + r;
      if (node < n) {
        const int d = cnt[node];
        const float rdeg = 1.0f / (float)(d > 1 ? d : 1);
        const float4 xv = *(const float4*)&xin[(size_t)node * 128 + f0];
        float4 m = *(const float4*)&xm[r * 128 + f0];
        m.x = epsv * xv.x + m.x * rdeg;
        m.y = epsv * xv.y + m.y * rdeg;
        m.z = epsv * xv.z + m.z * rdeg;
        m.w = epsv * xv.w + m.w * rdeg;
        *(float4*)&xm[r * 128 + f0] = m;
      } else {
        *(float4*)&xm[r * 128 + f0] = make_float4(0.f, 0.f, 0.f, 0.f);
      }
    }
  }
  __syncthreads();

  // ---- stage 3: GEMM, thread tile = 4 rows x 4 features ----
  {
    const int fg = t & 31;
    const int rg = t >> 5;
    const int f0 = fg * 4;
    const int r0 = rg * 4;
    float4 acc[4];
#pragma unroll
    for (int r = 0; r < 4; ++r) acc[r] = make_float4(0.f, 0.f, 0.f, 0.f);
    for (int k = 0; k < 128; k += 4) {
      const float4 w0 = *(const float4*)&Wt[(k + 0) * 128 + f0];
      const float4 w1 = *(const float4*)&Wt[(k + 1) * 128 + f0];
      const float4 w2 = *(const float4*)&Wt[(k + 2) * 128 + f0];
      const float4 w3 = *(const float4*)&Wt[(k + 3) * 128 + f0];
#pragma unroll
      for (int r = 0; r < 4; ++r) {
        const float4 xv = *(const float4*)&xm[(r0 + r) * 128 + k];
        acc[r].x += xv.x * w0.x + xv.y * w1.x + xv.z * w2.x + xv.w * w3.x;
        acc[r].y += xv.x * w0.y + xv.y * w1.y + xv.z * w2.y + xv.w * w3.y;
        acc[r].z += xv.x * w0.z + xv.y * w1.z + xv.z * w2.z + xv.w * w3.z;
        acc[r].w += xv.x * w0.w + xv.y * w1.w + xv.z * w2.w + xv.w * w3.w;
      }
    }
    const float4 bv = *(const float4*)&bias[f0];
#pragma unroll
    for (int r = 0; r < 4; ++r) {
      const int node = nb + r0 + r;
      if (node < n) {
        float4 v;
        v.x = acc[r].x + bv.x;
        v.y = acc[r].y + bv.y;
        v.z = acc[r].z + bv.z;
        v.w = acc[r].w + bv.w;
        if (dorelu) {
          v.x = fmaxf(v.x, 0.f); v.y = fmaxf(v.y, 0.f);
          v.z = fmaxf(v.z, 0.f); v.w = fmaxf(v.w, 0.f);
        }
        if (zerorow0 && node == 0) { v.x = 0.f; v.y = 0.f; v.z = 0.f; v.w = 0.f; }
        *(float4*)&xout[(size_t)node * 128 + f0] = v;
      }
    }
  }
}

// Tiled final MLP: 16 batch elements per 256-thread block (256 blocks total).
// Phase A: gather ing1/ing2/ctx rows into LDS (both halves split ctx 10/10,
// combine via LDS atomicAdd). Phase B: 16x384 @ 384x128 + ReLU.
// Phase C: 16x128 @ 128x64 + ReLU. Phase D: 16 dot-64 reductions.
// Weights are read ONCE per 16 elements (50 MB total vs 800 MB before).
__launch_bounds__(256, 4)
__global__ void final_kernel(const float* __restrict__ x2, const int* __restrict__ indices,
                             const float* __restrict__ Wc1t, const float* __restrict__ bc1,
                             const float* __restrict__ Wc2t, const float* __restrict__ bc2,
                             const float* __restrict__ Wc3, const float* __restrict__ bc3,
                             float* __restrict__ out) {
  __shared__ float ysm[16 * 384];
  __shared__ float h1s[16 * 128];
  __shared__ float h2s[16 * 64];
  __shared__ float ccs[16];
  const int t = threadIdx.x;
  const int b0 = blockIdx.x * 16;

  // zero ctx slots + per-element ctx counts
#pragma unroll
  for (int q = 0; q < 8; ++q) {
    const int s = t + q * 256;                 // 2048 = 16 x 128 ctx slots
    ysm[(s >> 7) * 384 + 256 + (s & 127)] = 0.f;
  }
  if (t < 16) {
    const int* ind = indices + (size_t)(b0 + t) * 23;
    int cc = 0;
#pragma unroll
    for (int j = 0; j < 20; ++j) cc += (ind[3 + j] > 0) ? 1 : 0;
    ccs[t] = 1.0f / (float)(cc > 0 ? cc : 1);
  }
  __syncthreads();

  // ---- phase A: gather ----
  {
    const int f = t & 127;
    const int half = t >> 7;
#pragma unroll 1
    for (int e = 0; e < 16; ++e) {
      const int* ind = indices + (size_t)(b0 + e) * 23;
      const int ing = ind[half];
      ysm[e * 384 + half * 128 + f] = x2[(size_t)ing * 128 + f];
      float cs = 0.f;
#pragma unroll
      for (int j = 0; j < 10; ++j) {
        const int cj = ind[3 + half * 10 + j];
        cs += x2[(size_t)cj * 128 + f];
      }
      atomicAdd(&ysm[e * 384 + 256 + f], cs);
    }
  }
  __syncthreads();
  // normalize ctx
#pragma unroll
  for (int q = 0; q < 8; ++q) {
    const int s = t + q * 256;
    const int e = s >> 7;
    ysm[e * 384 + 256 + (s & 127)] *= ccs[e];
  }
  __syncthreads();

  // ---- phase B: layer 1 (384 -> 128), 8 elems per thread ----
  {
    const int f1 = t & 127;
    const int eh = t >> 7;                     // elems eh*8 .. eh*8+7
    float acc[8];
    const float b = bc1[f1];
#pragma unroll
    for (int i = 0; i < 8; ++i) acc[i] = b;
    for (int k = 0; k < 384; k += 4) {
      const float wv0 = Wc1t[(k + 0) * 128 + f1];
      const float wv1 = Wc1t[(k + 1) * 128 + f1];
      const float wv2 = Wc1t[(k + 2) * 128 + f1];
      const float wv3 = Wc1t[(k + 3) * 128 + f1];
#pragma unroll
      for (int i = 0; i < 8; ++i) {
        const float4 yv = *(const float4*)&ysm[(eh * 8 + i) * 384 + k];
        acc[i] += yv.x * wv0 + yv.y * wv1 + yv.z * wv2 + yv.w * wv3;
      }
    }
#pragma unroll
    for (int i = 0; i < 8; ++i)
      h1s[(eh * 8 + i) * 128 + f1] = fmaxf(acc[i], 0.f);
  }
  __syncthreads();

  // ---- phase C: layer 2 (128 -> 64), 4 elems per thread ----
  {
    const int f2 = t & 63;
    const int eg = t >> 6;                     // elems eg*4 .. eg*4+3
    float acc[4];
    const float b = bc2[f2];
#pragma unroll
    for (int i = 0; i < 4; ++i) acc[i] = b;
    for (int k = 0; k < 128; k += 4) {
      const float wv0 = Wc2t[(k + 0) * 64 + f2];
      const float wv1 = Wc2t[(k + 1) * 64 + f2];
      const float wv2 = Wc2t[(k + 2) * 64 + f2];
      const float wv3 = Wc2t[(k + 3) * 64 + f2];
#pragma unroll
      for (int i = 0; i < 4; ++i) {
        const float4 hv = *(const float4*)&h1s[(eg * 4 + i) * 128 + k];
        acc[i] += hv.x * wv0 + hv.y * wv1 + hv.z * wv2 + hv.w * wv3;
      }
    }
#pragma unroll
    for (int i = 0; i < 4; ++i)
      h2s[(eg * 4 + i) * 64 + f2] = fmaxf(acc[i], 0.f);
  }
  __syncthreads();

  // ---- phase D: layer 3 (64 -> 1), 16 lanes per element ----
  {
    const int e = t >> 4;
    const int l = t & 15;
    float p = 0.f;
#pragma unroll
    for (int k = 0; k < 4; ++k)
      p += h2s[e * 64 + l + k * 16] * Wc3[l + k * 16];
#pragma unroll
    for (int o = 8; o > 0; o >>= 1) p += __shfl_down(p, o, 16);
    if (l == 0) out[b0 + e] = p + bc3[0];
  }
}

extern "C" void kernel_launch(void* const* d_in, const int* in_sizes, int n_in,
                              void* d_out, int out_size, void* d_ws, size_t ws_size,
                              hipStream_t stream) {
  const int* indices = (const int*)d_in[0];
  const int* src = (const int*)d_in[1];
  const int* dst = (const int*)d_in[2];
  const float* w = (const float*)d_in[3];
  const float* ndata = (const float*)d_in[4];
  const float* W1 = (const float*)d_in[5];
  const float* b1 = (const float*)d_in[6];
  const float* W2 = (const float*)d_in[7];
  const float* b2 = (const float*)d_in[8];
  const float* eps = (const float*)d_in[9];
  const float* Wc1 = (const float*)d_in[10];
  const float* bc1 = (const float*)d_in[11];
  const float* Wc2 = (const float*)d_in[12];
  const float* bc2 = (const float*)d_in[13];
  const float* Wc3 = (const float*)d_in[14];
  const float* bc3 = (const float*)d_in[15];
  float* out = (float*)d_out;

  const int E = in_sizes[1];
  const int N = in_sizes[4] / 128;
  const int B = in_sizes[0] / 23;

  char* ws = (char*)d_ws;
  size_t off = 0;
  auto alloc = [&](size_t bytes) -> char* {
    char* p = ws + off;
    off = (off + bytes + 255) & ~(size_t)255;
    return p;
  };
  const size_t Epad = (size_t)E + 8 * (size_t)N;   // worst-case padded edge count
  int* cnt = (int*)alloc((size_t)N * 4);
  int* prow = (int*)alloc((size_t)(N + 1) * 4);
  int* rank = (int*)alloc((size_t)E * 4);
  int* bsum = (int*)alloc(256 * 4);
  int2* epack = (int2*)alloc(Epad * 8);
  float* x1 = (float*)alloc((size_t)N * 128 * 4);
  float* x2 = (float*)alloc((size_t)N * 128 * 4);
  float* Wt1 = (float*)alloc(16384 * 4);
  float* Wt2 = (float*)alloc(16384 * 4);
  float* Wc1t = (float*)alloc(49152 * 4);
  float* Wc2t = (float*)alloc(8192 * 4);

  hipMemsetAsync(cnt, 0, (size_t)N * 4, stream);
  hipMemsetAsync(epack, 0, Epad * 8, stream);      // pad slots -> (src=0, w=0)

  prep_transpose<<<(90112 + 255) / 256, 256, 0, stream>>>(W1, W2, Wc1, Wc2, Wt1, Wt2, Wc1t, Wc2t);
  hist_kernel<<<(E + 255) / 256, 256, 0, stream>>>(dst, cnt, rank, E);
  const int nchunk = (N + 2047) / 2048;
  scan1_kernel<<<nchunk, 256, 0, stream>>>(cnt, prow, bsum, N);
  scan2_kernel<<<1, 64, 0, stream>>>(bsum, nchunk);
  scan3_kernel<<<(N + 255) / 256, 256, 0, stream>>>(prow, bsum, N, nchunk);
  scatter_kernel<<<(E + 255) / 256, 256, 0, stream>>>(src, dst, w, prow, rank, epack, E);

  const int nconv = (N + CONV_NPB - 1) / CONV_NPB;
  conv_kernel<<<nconv, 256, 0, stream>>>(ndata, x1, prow, cnt, epack, Wt1, b1, eps, 0, 1, 0, N);
  conv_kernel<<<nconv, 256, 0, stream>>>(x1, x2, prow, cnt, epack, Wt2, b2, eps, 1, 0, 1, N);

  final_kernel<<<B / 16, 256, 0, stream>>>(x2, indices, Wc1t, bc1, Wc2t, bc2, Wc3, bc3, out);
}

// Round 9
// 601.389 us; speedup vs baseline: 1.2091x; 1.2091x over previous
//
#include <hip/hip_runtime.h>

// GIN_MLP: 2x GIN conv (N=100000, E=1.6M, H=128) + per-batch context MLP (B=4096).
// Device-built dst-CSR (rank-based atomic-free scatter, 8-aligned padded rows)
// -> fused aggregate+GEMM (R7 laneset-f4 gather: the proven structure)
// -> 16-elem tiled final MLP (R8). All f32.
// R9: consolidation. scan3 folded into scatter+conv (bsum added on the fly),
// cnt-zeroing merged into the init kernel. 9 dispatches total.

#define CONV_NPB 32

// init: weight transposes + cnt zeroing (grid covers max(N, 90112))
__global__ void init_kernel(const float* __restrict__ W1, const float* __restrict__ W2,
                            const float* __restrict__ Wc1, const float* __restrict__ Wc2,
                            float* __restrict__ Wt1, float* __restrict__ Wt2,
                            float* __restrict__ Wc1t, float* __restrict__ Wc2t,
                            int* __restrict__ cnt, int n) {
  int i = blockIdx.x * blockDim.x + threadIdx.x;
  if (i < n) cnt[i] = 0;
  if (i < 16384) {
    int f = i >> 7, k = i & 127;
    Wt1[k * 128 + f] = W1[i];
  } else if (i < 32768) {
    int j = i - 16384; int f = j >> 7, k = j & 127;
    Wt2[k * 128 + f] = W2[j];
  } else if (i < 81920) {
    int j = i - 32768; int f = j / 384, k = j % 384;
    Wc1t[k * 128 + f] = Wc1[j];
  } else if (i < 90112) {
    int j = i - 81920; int f = j >> 7, k = j & 127;
    Wc2t[k * 64 + f] = Wc2[j];
  }
}

// counts per-dst degree AND records each edge's arrival rank (makes scatter atomic-free)
__global__ void hist_kernel(const int* __restrict__ dst, int* __restrict__ cnt,
                            int* __restrict__ rank, int E) {
  int e = blockIdx.x * blockDim.x + threadIdx.x;
  if (e < E) rank[e] = atomicAdd(&cnt[dst[e]], 1);
}

// per-2048-chunk exclusive scan of PADDED counts (ceil(cnt/8)*8); bsum[b] = chunk total
__global__ void scan1_kernel(const int* __restrict__ cnt, int* __restrict__ prow,
                             int* __restrict__ bsum, int n) {
  __shared__ int smem[256];
  const int t = threadIdx.x;
  const int base = blockIdx.x * 2048 + t * 8;
  int v[8];
  int s = 0;
#pragma unroll
  for (int j = 0; j < 8; ++j) {
    int idx = base + j;
    v[j] = (idx < n) ? ((cnt[idx] + 7) & ~7) : 0;
    s += v[j];
  }
  smem[t] = s;
  __syncthreads();
  for (int off = 1; off < 256; off <<= 1) {
    int add = (t >= off) ? smem[t - off] : 0;
    __syncthreads();
    smem[t] += add;
    __syncthreads();
  }
  int run = smem[t] - s;
  if (t == 255) bsum[blockIdx.x] = smem[255];
#pragma unroll
  for (int j = 0; j < 8; ++j) {
    int idx = base + j;
    if (idx < n) prow[idx] = run;
    run += v[j];
  }
}

// 64-lane shuffle scan (nchunk=49 fits); appends grand total at bsum[nb]
__global__ void scan2_kernel(int* __restrict__ bsum, int nb) {
  const int t = threadIdx.x;
  if (nb <= 64) {
    const int orig = (t < nb) ? bsum[t] : 0;
    int v = orig;
#pragma unroll
    for (int off = 1; off < 64; off <<= 1) {
      int u = __shfl_up(v, off);
      if (t >= off) v += u;
    }
    if (t == nb - 1) bsum[nb] = v;
    if (t < nb) bsum[t] = v - orig;
  } else if (t == 0) {
    int run = 0;
    for (int i = 0; i < nb; ++i) { int v = bsum[i]; bsum[i] = run; run += v; }
    bsum[nb] = run;
  }
}

// atomic-free scatter into padded CSR; bsum correction applied inline (no scan3)
__global__ void scatter_kernel(const int* __restrict__ src, const int* __restrict__ dst,
                               const float* __restrict__ w, const int* __restrict__ prow,
                               const int* __restrict__ bsum,
                               const int* __restrict__ rank, int2* __restrict__ epack, int E) {
  int e = blockIdx.x * blockDim.x + threadIdx.x;
  if (e < E) {
    const int d = dst[e];
    const int pos = prow[d] + bsum[d >> 11] + rank[e];
    epack[pos] = make_int2(src[e], __float_as_int(w[e]));
  }
}

// Stage 1 (R7, proven): block's 32 rows = contiguous 8-aligned padded edge
// range, split into 8 laneset chunks (multiples of 8). Per 8-edge batch:
// 4 int4 descriptor loads + 8 independent float4 gathers + 32 FMA,
// straight-line; register acc flushes to LDS (permuted, bank=lane) only at row
// transitions. Stage 2: de-permute + (1+eps)x + agg/deg. Stage 3: GEMM.
__launch_bounds__(256, 6)
__global__ void conv_kernel(const float* __restrict__ xin, float* __restrict__ xout,
                            const int* __restrict__ prow, const int* __restrict__ bsum,
                            const int* __restrict__ cnt,
                            const int2* __restrict__ epack,
                            const float* __restrict__ Wt,
                            const float* __restrict__ bias, const float* __restrict__ eps,
                            int epsidx, int dorelu, int zerorow0, int n, int nchunk) {
  __shared__ float xm[CONV_NPB * 128];
  __shared__ int rp_s[CONV_NPB + 1];
  const int t = threadIdx.x;
  const int nb = blockIdx.x * CONV_NPB;
  const float epsv = 1.0f + eps[epsidx];

  // zero accumulator tile + cache padded rowptr slice (bsum folded in)
#pragma unroll
  for (int i = 0; i < 4; ++i)
    *(float4*)&xm[(t + i * 256) * 4] = make_float4(0.f, 0.f, 0.f, 0.f);
  if (t <= CONV_NPB) {
    const int node = nb + t;
    rp_s[t] = (node >= n) ? bsum[nchunk] : (prow[node] + bsum[node >> 11]);
  }
  __syncthreads();

  // ---- stage 1: padded 8-batch laneset-f4 gather ----
  {
    const int L = t >> 5;          // laneset 0..7
    const int lane = t & 31;
    const int f0 = lane * 4;
    const int e0 = rp_s[0], eT = rp_s[CONV_NPB];
    const int nbat = (eT - e0) >> 3;             // total 8-batches (8-aligned)
    const int chunk = (((nbat + 7) >> 3)) << 3;  // edges per laneset, mult of 8
    const int jb = e0 + L * chunk;
    const int je = min(jb + chunk, eT);
    if (jb < je) {
      const int4* ep4 = (const int4*)epack;      // (src0,w0,src1,w1)
      int r = 0;
      while (rp_s[r + 1] <= jb) ++r;
      float4 acc = make_float4(0.f, 0.f, 0.f, 0.f);
      for (int j = jb; j < je; j += 8) {
        if (rp_s[r + 1] <= j) {                  // new row: flush (permuted, bank=lane)
          float* bp = &xm[r * 128 + lane];
          atomicAdd(bp + 0,  acc.x);
          atomicAdd(bp + 32, acc.y);
          atomicAdd(bp + 64, acc.z);
          atomicAdd(bp + 96, acc.w);
          acc = make_float4(0.f, 0.f, 0.f, 0.f);
          do { ++r; } while (rp_s[r + 1] <= j);
        }
        const int h = j >> 1;
        const int4 q0 = ep4[h + 0];
        const int4 q1 = ep4[h + 1];
        const int4 q2 = ep4[h + 2];
        const int4 q3 = ep4[h + 3];
        const float4 a0 = *(const float4*)&xin[(size_t)q0.x * 128 + f0];
        const float4 a1 = *(const float4*)&xin[(size_t)q0.z * 128 + f0];
        const float4 a2 = *(const float4*)&xin[(size_t)q1.x * 128 + f0];
        const float4 a3 = *(const float4*)&xin[(size_t)q1.z * 128 + f0];
        const float4 a4 = *(const float4*)&xin[(size_t)q2.x * 128 + f0];
        const float4 a5 = *(const float4*)&xin[(size_t)q2.z * 128 + f0];
        const float4 a6 = *(const float4*)&xin[(size_t)q3.x * 128 + f0];
        const float4 a7 = *(const float4*)&xin[(size_t)q3.z * 128 + f0];
        const float w0 = __int_as_float(q0.y), w1 = __int_as_float(q0.w);
        const float w2 = __int_as_float(q1.y), w3 = __int_as_float(q1.w);
        const float w4 = __int_as_float(q2.y), w5 = __int_as_float(q2.w);
        const float w6 = __int_as_float(q3.y), w7 = __int_as_float(q3.w);
        acc.x += w0 * a0.x + w1 * a1.x + w2 * a2.x + w3 * a3.x
               + w4 * a4.x + w5 * a5.x + w6 * a6.x + w7 * a7.x;
        acc.y += w0 * a0.y + w1 * a1.y + w2 * a2.y + w3 * a3.y
               + w4 * a4.y + w5 * a5.y + w6 * a6.y + w7 * a7.y;
        acc.z += w0 * a0.z + w1 * a1.z + w2 * a2.z + w3 * a3.z
               + w4 * a4.z + w5 * a5.z + w6 * a6.z + w7 * a7.z;
        acc.w += w0 * a0.w + w1 * a1.w + w2 * a2.w + w3 * a3.w
               + w4 * a4.w + w5 * a5.w + w6 * a6.w + w7 * a7.w;
      }
      float* bp = &xm[r * 128 + lane];
      atomicAdd(bp + 0,  acc.x);
      atomicAdd(bp + 32, acc.y);
      atomicAdd(bp + 64, acc.z);
      atomicAdd(bp + 96, acc.w);
    }
  }
  __syncthreads();

  // ---- stage 2: de-permute + finalize (1+eps)*x + agg/deg ----
  {
    float4 m[4];
#pragma unroll
    for (int q = 0; q < 4; ++q) {
      const int task = t + q * 256;             // 32 rows x 32 fgroups
      const int r = task >> 5;
      const int fg = task & 31;
      m[q].x = xm[r * 128 + fg];
      m[q].y = xm[r * 128 + 32 + fg];
      m[q].z = xm[r * 128 + 64 + fg];
      m[q].w = xm[r * 128 + 96 + fg];
    }
    __syncthreads();
#pragma unroll
    for (int q = 0; q < 4; ++q) {
      const int task = t + q * 256;
      const int r = task >> 5;
      const int fg = task & 31;
      const int f0 = fg * 4;
      const int node = nb + r;
      float4 v = make_float4(0.f, 0.f, 0.f, 0.f);
      if (node < n) {
        const int d = cnt[node];
        const float rdeg = 1.0f / (float)(d > 1 ? d : 1);
        const float4 xv = *(const float4*)&xin[(size_t)node * 128 + f0];
        v.x = epsv * xv.x + m[q].x * rdeg;
        v.y = epsv * xv.y + m[q].y * rdeg;
        v.z = epsv * xv.z + m[q].z * rdeg;
        v.w = epsv * xv.w + m[q].w * rdeg;
      }
      *(float4*)&xm[r * 128 + f0] = v;
    }
  }
  __syncthreads();

  // ---- stage 3: GEMM, thread tile = 4 rows x 4 features ----
  {
    const int fg = t & 31;
    const int rg = t >> 5;
    const int f0 = fg * 4;
    const int r0 = rg * 4;
    float4 acc[4];
#pragma unroll
    for (int r = 0; r < 4; ++r) acc[r] = make_float4(0.f, 0.f, 0.f, 0.f);
    for (int k = 0; k < 128; k += 4) {
      const float4 w0 = *(const float4*)&Wt[(k + 0) * 128 + f0];
      const float4 w1 = *(const float4*)&Wt[(k + 1) * 128 + f0];
      const float4 w2 = *(const float4*)&Wt[(k + 2) * 128 + f0];
      const float4 w3 = *(const float4*)&Wt[(k + 3) * 128 + f0];
#pragma unroll
      for (int r = 0; r < 4; ++r) {
        const float4 xv = *(const float4*)&xm[(r0 + r) * 128 + k];
        acc[r].x += xv.x * w0.x + xv.y * w1.x + xv.z * w2.x + xv.w * w3.x;
        acc[r].y += xv.x * w0.y + xv.y * w1.y + xv.z * w2.y + xv.w * w3.y;
        acc[r].z += xv.x * w0.z + xv.y * w1.z + xv.z * w2.z + xv.w * w3.z;
        acc[r].w += xv.x * w0.w + xv.y * w1.w + xv.z * w2.w + xv.w * w3.w;
      }
    }
    const float4 bv = *(const float4*)&bias[f0];
#pragma unroll
    for (int r = 0; r < 4; ++r) {
      const int node = nb + r0 + r;
      if (node < n) {
        float4 v;
        v.x = acc[r].x + bv.x;
        v.y = acc[r].y + bv.y;
        v.z = acc[r].z + bv.z;
        v.w = acc[r].w + bv.w;
        if (dorelu) {
          v.x = fmaxf(v.x, 0.f); v.y = fmaxf(v.y, 0.f);
          v.z = fmaxf(v.z, 0.f); v.w = fmaxf(v.w, 0.f);
        }
        if (zerorow0 && node == 0) { v.x = 0.f; v.y = 0.f; v.z = 0.f; v.w = 0.f; }
        *(float4*)&xout[(size_t)node * 128 + f0] = v;
      }
    }
  }
}

// Tiled final MLP (R8, proven): 16 batch elements per 256-thread block.
__launch_bounds__(256, 4)
__global__ void final_kernel(const float* __restrict__ x2, const int* __restrict__ indices,
                             const float* __restrict__ Wc1t, const float* __restrict__ bc1,
                             const float* __restrict__ Wc2t, const float* __restrict__ bc2,
                             const float* __restrict__ Wc3, const float* __restrict__ bc3,
                             float* __restrict__ out) {
  __shared__ float ysm[16 * 384];
  __shared__ float h1s[16 * 128];
  __shared__ float h2s[16 * 64];
  __shared__ float ccs[16];
  const int t = threadIdx.x;
  const int b0 = blockIdx.x * 16;

#pragma unroll
  for (int q = 0; q < 8; ++q) {
    const int s = t + q * 256;
    ysm[(s >> 7) * 384 + 256 + (s & 127)] = 0.f;
  }
  if (t < 16) {
    const int* ind = indices + (size_t)(b0 + t) * 23;
    int cc = 0;
#pragma unroll
    for (int j = 0; j < 20; ++j) cc += (ind[3 + j] > 0) ? 1 : 0;
    ccs[t] = 1.0f / (float)(cc > 0 ? cc : 1);
  }
  __syncthreads();

  // ---- phase A: gather ----
  {
    const int f = t & 127;
    const int half = t >> 7;
#pragma unroll 1
    for (int e = 0; e < 16; ++e) {
      const int* ind = indices + (size_t)(b0 + e) * 23;
      const int ing = ind[half];
      ysm[e * 384 + half * 128 + f] = x2[(size_t)ing * 128 + f];
      float cs = 0.f;
#pragma unroll
      for (int j = 0; j < 10; ++j) {
        const int cj = ind[3 + half * 10 + j];
        cs += x2[(size_t)cj * 128 + f];
      }
      atomicAdd(&ysm[e * 384 + 256 + f], cs);
    }
  }
  __syncthreads();
#pragma unroll
  for (int q = 0; q < 8; ++q) {
    const int s = t + q * 256;
    const int e = s >> 7;
    ysm[e * 384 + 256 + (s & 127)] *= ccs[e];
  }
  __syncthreads();

  // ---- phase B: layer 1 (384 -> 128), 8 elems per thread ----
  {
    const int f1 = t & 127;
    const int eh = t >> 7;
    float acc[8];
    const float b = bc1[f1];
#pragma unroll
    for (int i = 0; i < 8; ++i) acc[i] = b;
    for (int k = 0; k < 384; k += 4) {
      const float wv0 = Wc1t[(k + 0) * 128 + f1];
      const float wv1 = Wc1t[(k + 1) * 128 + f1];
      const float wv2 = Wc1t[(k + 2) * 128 + f1];
      const float wv3 = Wc1t[(k + 3) * 128 + f1];
#pragma unroll
      for (int i = 0; i < 8; ++i) {
        const float4 yv = *(const float4*)&ysm[(eh * 8 + i) * 384 + k];
        acc[i] += yv.x * wv0 + yv.y * wv1 + yv.z * wv2 + yv.w * wv3;
      }
    }
#pragma unroll
    for (int i = 0; i < 8; ++i)
      h1s[(eh * 8 + i) * 128 + f1] = fmaxf(acc[i], 0.f);
  }
  __syncthreads();

  // ---- phase C: layer 2 (128 -> 64), 4 elems per thread ----
  {
    const int f2 = t & 63;
    const int eg = t >> 6;
    float acc[4];
    const float b = bc2[f2];
#pragma unroll
    for (int i = 0; i < 4; ++i) acc[i] = b;
    for (int k = 0; k < 128; k += 4) {
      const float wv0 = Wc2t[(k + 0) * 64 + f2];
      const float wv1 = Wc2t[(k + 1) * 64 + f2];
      const float wv2 = Wc2t[(k + 2) * 64 + f2];
      const float wv3 = Wc2t[(k + 3) * 64 + f2];
#pragma unroll
      for (int i = 0; i < 4; ++i) {
        const float4 hv = *(const float4*)&h1s[(eg * 4 + i) * 128 + k];
        acc[i] += hv.x * wv0 + hv.y * wv1 + hv.z * wv2 + hv.w * wv3;
      }
    }
#pragma unroll
    for (int i = 0; i < 4; ++i)
      h2s[(eg * 4 + i) * 64 + f2] = fmaxf(acc[i], 0.f);
  }
  __syncthreads();

  // ---- phase D: layer 3 (64 -> 1), 16 lanes per element ----
  {
    const int e = t >> 4;
    const int l = t & 15;
    float p = 0.f;
#pragma unroll
    for (int k = 0; k < 4; ++k)
      p += h2s[e * 64 + l + k * 16] * Wc3[l + k * 16];
#pragma unroll
    for (int o = 8; o > 0; o >>= 1) p += __shfl_down(p, o, 16);
    if (l == 0) out[b0 + e] = p + bc3[0];
  }
}

extern "C" void kernel_launch(void* const* d_in, const int* in_sizes, int n_in,
                              void* d_out, int out_size, void* d_ws, size_t ws_size,
                              hipStream_t stream) {
  const int* indices = (const int*)d_in[0];
  const int* src = (const int*)d_in[1];
  const int* dst = (const int*)d_in[2];
  const float* w = (const float*)d_in[3];
  const float* ndata = (const float*)d_in[4];
  const float* W1 = (const float*)d_in[5];
  const float* b1 = (const float*)d_in[6];
  const float* W2 = (const float*)d_in[7];
  const float* b2 = (const float*)d_in[8];
  const float* eps = (const float*)d_in[9];
  const float* Wc1 = (const float*)d_in[10];
  const float* bc1 = (const float*)d_in[11];
  const float* Wc2 = (const float*)d_in[12];
  const float* bc2 = (const float*)d_in[13];
  const float* Wc3 = (const float*)d_in[14];
  const float* bc3 = (const float*)d_in[15];
  float* out = (float*)d_out;

  const int E = in_sizes[1];
  const int N = in_sizes[4] / 128;
  const int B = in_sizes[0] / 23;

  char* ws = (char*)d_ws;
  size_t off = 0;
  auto alloc = [&](size_t bytes) -> char* {
    char* p = ws + off;
    off = (off + bytes + 255) & ~(size_t)255;
    return p;
  };
  const size_t Epad = (size_t)E + 8 * (size_t)N;   // worst-case padded edge count
  int* cnt = (int*)alloc((size_t)N * 4);
  int* prow = (int*)alloc((size_t)(N + 1) * 4);
  int* rank = (int*)alloc((size_t)E * 4);
  int* bsum = (int*)alloc(256 * 4);
  int2* epack = (int2*)alloc(Epad * 8);
  float* x1 = (float*)alloc((size_t)N * 128 * 4);
  float* x2 = (float*)alloc((size_t)N * 128 * 4);
  float* Wt1 = (float*)alloc(16384 * 4);
  float* Wt2 = (float*)alloc(16384 * 4);
  float* Wc1t = (float*)alloc(49152 * 4);
  float* Wc2t = (float*)alloc(8192 * 4);

  hipMemsetAsync(epack, 0, Epad * 8, stream);      // pad slots -> (src=0, w=0)

  const int ninit = (N > 90112) ? N : 90112;
  init_kernel<<<(ninit + 255) / 256, 256, 0, stream>>>(W1, W2, Wc1, Wc2, Wt1, Wt2, Wc1t, Wc2t, cnt, N);
  hist_kernel<<<(E + 255) / 256, 256, 0, stream>>>(dst, cnt, rank, E);
  const int nchunk = (N + 2047) / 2048;
  scan1_kernel<<<nchunk, 256, 0, stream>>>(cnt, prow, bsum, N);
  scan2_kernel<<<1, 64, 0, stream>>>(bsum, nchunk);
  scatter_kernel<<<(E + 255) / 256, 256, 0, stream>>>(src, dst, w, prow, bsum, rank, epack, E);

  const int nconv = (N + CONV_NPB - 1) / CONV_NPB;
  conv_kernel<<<nconv, 256, 0, stream>>>(ndata, x1, prow, bsum, cnt, epack, Wt1, b1, eps, 0, 1, 0, N, nchunk);
  conv_kernel<<<nconv, 256, 0, stream>>>(x1, x2, prow, bsum, cnt, epack, Wt2, b2, eps, 1, 0, 1, N, nchunk);

  final_kernel<<<B / 16, 256, 0, stream>>>(x2, indices, Wc1t, bc1, Wc2t, bc2, Wc3, bc3, out);
}

// Round 10
// 597.640 us; speedup vs baseline: 1.2167x; 1.0063x over previous
//
#include <hip/hip_runtime.h>

// GIN_MLP: 2x GIN conv (N=100000, E=1.6M, H=128) + per-batch context MLP (B=4096).
// Device-built dst-CSR (rank-based atomic-free scatter, 8-aligned padded rows)
// -> fused aggregate+GEMM (R7 laneset-f4 gather, proven 176 us: transaction-
// rate wall ~2 lines/cy/XCD) -> tiled final MLP. All f32.
// R10: final_kernel rewritten: 8 elems/block (512 blocks), LDS-staged indices,
// phase A = per-thread 20 INDEPENDENT float4 ctx gathers + register acc (no LDS
// atomics, no serialization); hist/scatter process 2 edges/thread.

#define CONV_NPB 32
#define FIN_EPB 8

// init: weight transposes + cnt zeroing (grid covers max(N, 90112))
__global__ void init_kernel(const float* __restrict__ W1, const float* __restrict__ W2,
                            const float* __restrict__ Wc1, const float* __restrict__ Wc2,
                            float* __restrict__ Wt1, float* __restrict__ Wt2,
                            float* __restrict__ Wc1t, float* __restrict__ Wc2t,
                            int* __restrict__ cnt, int n) {
  int i = blockIdx.x * blockDim.x + threadIdx.x;
  if (i < n) cnt[i] = 0;
  if (i < 16384) {
    int f = i >> 7, k = i & 127;
    Wt1[k * 128 + f] = W1[i];
  } else if (i < 32768) {
    int j = i - 16384; int f = j >> 7, k = j & 127;
    Wt2[k * 128 + f] = W2[j];
  } else if (i < 81920) {
    int j = i - 32768; int f = j / 384, k = j % 384;
    Wc1t[k * 128 + f] = Wc1[j];
  } else if (i < 90112) {
    int j = i - 81920; int f = j >> 7, k = j & 127;
    Wc2t[k * 64 + f] = Wc2[j];
  }
}

// counts per-dst degree AND records each edge's arrival rank; 2 edges/thread
__global__ void hist_kernel(const int* __restrict__ dst, int* __restrict__ cnt,
                            int* __restrict__ rank, int E) {
  int e = (blockIdx.x * blockDim.x + threadIdx.x) * 2;
  if (e + 1 < E) {
    const int2 d = *(const int2*)&dst[e];
    const int r0 = atomicAdd(&cnt[d.x], 1);
    const int r1 = atomicAdd(&cnt[d.y], 1);
    *(int2*)&rank[e] = make_int2(r0, r1);
  } else if (e < E) {
    rank[e] = atomicAdd(&cnt[dst[e]], 1);
  }
}

// per-2048-chunk exclusive scan of PADDED counts (ceil(cnt/8)*8); bsum[b] = chunk total
__global__ void scan1_kernel(const int* __restrict__ cnt, int* __restrict__ prow,
                             int* __restrict__ bsum, int n) {
  __shared__ int smem[256];
  const int t = threadIdx.x;
  const int base = blockIdx.x * 2048 + t * 8;
  int v[8];
  int s = 0;
#pragma unroll
  for (int j = 0; j < 8; ++j) {
    int idx = base + j;
    v[j] = (idx < n) ? ((cnt[idx] + 7) & ~7) : 0;
    s += v[j];
  }
  smem[t] = s;
  __syncthreads();
  for (int off = 1; off < 256; off <<= 1) {
    int add = (t >= off) ? smem[t - off] : 0;
    __syncthreads();
    smem[t] += add;
    __syncthreads();
  }
  int run = smem[t] - s;
  if (t == 255) bsum[blockIdx.x] = smem[255];
#pragma unroll
  for (int j = 0; j < 8; ++j) {
    int idx = base + j;
    if (idx < n) prow[idx] = run;
    run += v[j];
  }
}

// 64-lane shuffle scan (nchunk=49 fits); appends grand total at bsum[nb]
__global__ void scan2_kernel(int* __restrict__ bsum, int nb) {
  const int t = threadIdx.x;
  if (nb <= 64) {
    const int orig = (t < nb) ? bsum[t] : 0;
    int v = orig;
#pragma unroll
    for (int off = 1; off < 64; off <<= 1) {
      int u = __shfl_up(v, off);
      if (t >= off) v += u;
    }
    if (t == nb - 1) bsum[nb] = v;
    if (t < nb) bsum[t] = v - orig;
  } else if (t == 0) {
    int run = 0;
    for (int i = 0; i < nb; ++i) { int v = bsum[i]; bsum[i] = run; run += v; }
    bsum[nb] = run;
  }
}

// atomic-free scatter into padded CSR; 2 edges/thread; bsum folded in (no scan3)
__global__ void scatter_kernel(const int* __restrict__ src, const int* __restrict__ dst,
                               const float* __restrict__ w, const int* __restrict__ prow,
                               const int* __restrict__ bsum,
                               const int* __restrict__ rank, int2* __restrict__ epack, int E) {
  int e = (blockIdx.x * blockDim.x + threadIdx.x) * 2;
  if (e + 1 < E) {
    const int2 d = *(const int2*)&dst[e];
    const int2 s = *(const int2*)&src[e];
    const float2 wv = *(const float2*)&w[e];
    const int2 r = *(const int2*)&rank[e];
    const int p0 = prow[d.x] + bsum[d.x >> 11] + r.x;
    const int p1 = prow[d.y] + bsum[d.y >> 11] + r.y;
    epack[p0] = make_int2(s.x, __float_as_int(wv.x));
    epack[p1] = make_int2(s.y, __float_as_int(wv.y));
  } else if (e < E) {
    const int d = dst[e];
    const int pos = prow[d] + bsum[d >> 11] + rank[e];
    epack[pos] = make_int2(src[e], __float_as_int(w[e]));
  }
}

// Stage 1 (R7, proven): block's 32 rows = contiguous 8-aligned padded edge
// range, split into 8 laneset chunks (multiples of 8). Per 8-edge batch:
// 4 int4 descriptor loads + 8 independent float4 gathers + 32 FMA,
// straight-line; register acc flushes to LDS (permuted, bank=lane) only at row
// transitions. Stage 2: de-permute + (1+eps)x + agg/deg. Stage 3: GEMM.
__launch_bounds__(256, 6)
__global__ void conv_kernel(const float* __restrict__ xin, float* __restrict__ xout,
                            const int* __restrict__ prow, const int* __restrict__ bsum,
                            const int* __restrict__ cnt,
                            const int2* __restrict__ epack,
                            const float* __restrict__ Wt,
                            const float* __restrict__ bias, const float* __restrict__ eps,
                            int epsidx, int dorelu, int zerorow0, int n, int nchunk) {
  __shared__ float xm[CONV_NPB * 128];
  __shared__ int rp_s[CONV_NPB + 1];
  const int t = threadIdx.x;
  const int nb = blockIdx.x * CONV_NPB;
  const float epsv = 1.0f + eps[epsidx];

#pragma unroll
  for (int i = 0; i < 4; ++i)
    *(float4*)&xm[(t + i * 256) * 4] = make_float4(0.f, 0.f, 0.f, 0.f);
  if (t <= CONV_NPB) {
    const int node = nb + t;
    rp_s[t] = (node >= n) ? bsum[nchunk] : (prow[node] + bsum[node >> 11]);
  }
  __syncthreads();

  // ---- stage 1: padded 8-batch laneset-f4 gather ----
  {
    const int L = t >> 5;
    const int lane = t & 31;
    const int f0 = lane * 4;
    const int e0 = rp_s[0], eT = rp_s[CONV_NPB];
    const int nbat = (eT - e0) >> 3;
    const int chunk = (((nbat + 7) >> 3)) << 3;
    const int jb = e0 + L * chunk;
    const int je = min(jb + chunk, eT);
    if (jb < je) {
      const int4* ep4 = (const int4*)epack;
      int r = 0;
      while (rp_s[r + 1] <= jb) ++r;
      float4 acc = make_float4(0.f, 0.f, 0.f, 0.f);
      for (int j = jb; j < je; j += 8) {
        if (rp_s[r + 1] <= j) {
          float* bp = &xm[r * 128 + lane];
          atomicAdd(bp + 0,  acc.x);
          atomicAdd(bp + 32, acc.y);
          atomicAdd(bp + 64, acc.z);
          atomicAdd(bp + 96, acc.w);
          acc = make_float4(0.f, 0.f, 0.f, 0.f);
          do { ++r; } while (rp_s[r + 1] <= j);
        }
        const int h = j >> 1;
        const int4 q0 = ep4[h + 0];
        const int4 q1 = ep4[h + 1];
        const int4 q2 = ep4[h + 2];
        const int4 q3 = ep4[h + 3];
        const float4 a0 = *(const float4*)&xin[(size_t)q0.x * 128 + f0];
        const float4 a1 = *(const float4*)&xin[(size_t)q0.z * 128 + f0];
        const float4 a2 = *(const float4*)&xin[(size_t)q1.x * 128 + f0];
        const float4 a3 = *(const float4*)&xin[(size_t)q1.z * 128 + f0];
        const float4 a4 = *(const float4*)&xin[(size_t)q2.x * 128 + f0];
        const float4 a5 = *(const float4*)&xin[(size_t)q2.z * 128 + f0];
        const float4 a6 = *(const float4*)&xin[(size_t)q3.x * 128 + f0];
        const float4 a7 = *(const float4*)&xin[(size_t)q3.z * 128 + f0];
        const float w0 = __int_as_float(q0.y), w1 = __int_as_float(q0.w);
        const float w2 = __int_as_float(q1.y), w3 = __int_as_float(q1.w);
        const float w4 = __int_as_float(q2.y), w5 = __int_as_float(q2.w);
        const float w6 = __int_as_float(q3.y), w7 = __int_as_float(q3.w);
        acc.x += w0 * a0.x + w1 * a1.x + w2 * a2.x + w3 * a3.x
               + w4 * a4.x + w5 * a5.x + w6 * a6.x + w7 * a7.x;
        acc.y += w0 * a0.y + w1 * a1.y + w2 * a2.y + w3 * a3.y
               + w4 * a4.y + w5 * a5.y + w6 * a6.y + w7 * a7.y;
        acc.z += w0 * a0.z + w1 * a1.z + w2 * a2.z + w3 * a3.z
               + w4 * a4.z + w5 * a5.z + w6 * a6.z + w7 * a7.z;
        acc.w += w0 * a0.w + w1 * a1.w + w2 * a2.w + w3 * a3.w
               + w4 * a4.w + w5 * a5.w + w6 * a6.w + w7 * a7.w;
      }
      float* bp = &xm[r * 128 + lane];
      atomicAdd(bp + 0,  acc.x);
      atomicAdd(bp + 32, acc.y);
      atomicAdd(bp + 64, acc.z);
      atomicAdd(bp + 96, acc.w);
    }
  }
  __syncthreads();

  // ---- stage 2: de-permute + finalize (1+eps)*x + agg/deg ----
  {
    float4 m[4];
#pragma unroll
    for (int q = 0; q < 4; ++q) {
      const int task = t + q * 256;
      const int r = task >> 5;
      const int fg = task & 31;
      m[q].x = xm[r * 128 + fg];
      m[q].y = xm[r * 128 + 32 + fg];
      m[q].z = xm[r * 128 + 64 + fg];
      m[q].w = xm[r * 128 + 96 + fg];
    }
    __syncthreads();
#pragma unroll
    for (int q = 0; q < 4; ++q) {
      const int task = t + q * 256;
      const int r = task >> 5;
      const int fg = task & 31;
      const int f0 = fg * 4;
      const int node = nb + r;
      float4 v = make_float4(0.f, 0.f, 0.f, 0.f);
      if (node < n) {
        const int d = cnt[node];
        const float rdeg = 1.0f / (float)(d > 1 ? d : 1);
        const float4 xv = *(const float4*)&xin[(size_t)node * 128 + f0];
        v.x = epsv * xv.x + m[q].x * rdeg;
        v.y = epsv * xv.y + m[q].y * rdeg;
        v.z = epsv * xv.z + m[q].z * rdeg;
        v.w = epsv * xv.w + m[q].w * rdeg;
      }
      *(float4*)&xm[r * 128 + f0] = v;
    }
  }
  __syncthreads();

  // ---- stage 3: GEMM, thread tile = 4 rows x 4 features ----
  {
    const int fg = t & 31;
    const int rg = t >> 5;
    const int f0 = fg * 4;
    const int r0 = rg * 4;
    float4 acc[4];
#pragma unroll
    for (int r = 0; r < 4; ++r) acc[r] = make_float4(0.f, 0.f, 0.f, 0.f);
    for (int k = 0; k < 128; k += 4) {
      const float4 w0 = *(const float4*)&Wt[(k + 0) * 128 + f0];
      const float4 w1 = *(const float4*)&Wt[(k + 1) * 128 + f0];
      const float4 w2 = *(const float4*)&Wt[(k + 2) * 128 + f0];
      const float4 w3 = *(const float4*)&Wt[(k + 3) * 128 + f0];
#pragma unroll
      for (int r = 0; r < 4; ++r) {
        const float4 xv = *(const float4*)&xm[(r0 + r) * 128 + k];
        acc[r].x += xv.x * w0.x + xv.y * w1.x + xv.z * w2.x + xv.w * w3.x;
        acc[r].y += xv.x * w0.y + xv.y * w1.y + xv.z * w2.y + xv.w * w3.y;
        acc[r].z += xv.x * w0.z + xv.y * w1.z + xv.z * w2.z + xv.w * w3.z;
        acc[r].w += xv.x * w0.w + xv.y * w1.w + xv.z * w2.w + xv.w * w3.w;
      }
    }
    const float4 bv = *(const float4*)&bias[f0];
#pragma unroll
    for (int r = 0; r < 4; ++r) {
      const int node = nb + r0 + r;
      if (node < n) {
        float4 v;
        v.x = acc[r].x + bv.x;
        v.y = acc[r].y + bv.y;
        v.z = acc[r].z + bv.z;
        v.w = acc[r].w + bv.w;
        if (dorelu) {
          v.x = fmaxf(v.x, 0.f); v.y = fmaxf(v.y, 0.f);
          v.z = fmaxf(v.z, 0.f); v.w = fmaxf(v.w, 0.f);
        }
        if (zerorow0 && node == 0) { v.x = 0.f; v.y = 0.f; v.z = 0.f; v.w = 0.f; }
        *(float4*)&xout[(size_t)node * 128 + f0] = v;
      }
    }
  }
}

// Final MLP, R10: 8 elems per 256-thread block (512 blocks). Indices in LDS.
// Phase A: ing rows = 2 flat f4 loads/thread; ctx = each thread owns one
// (elem, fgroup) and sums 20 INDEPENDENT f4 gathers in registers (no atomics).
// Phase B: 384->128 (4 elems/thread). Phase C: 128->64 (2 elems/thread).
// Phase D: 64->1 (32 lanes/elem shuffle reduce).
__launch_bounds__(256, 4)
__global__ void final_kernel(const float* __restrict__ x2, const int* __restrict__ indices,
                             const float* __restrict__ Wc1t, const float* __restrict__ bc1,
                             const float* __restrict__ Wc2t, const float* __restrict__ bc2,
                             const float* __restrict__ Wc3, const float* __restrict__ bc3,
                             float* __restrict__ out) {
  __shared__ float ysm[FIN_EPB * 384];
  __shared__ float h1s[FIN_EPB * 128];
  __shared__ float h2s[FIN_EPB * 64];
  __shared__ int ind_s[FIN_EPB * 23];
  __shared__ float ccs[FIN_EPB];
  const int t = threadIdx.x;
  const int b0 = blockIdx.x * FIN_EPB;

  if (t < FIN_EPB * 23) ind_s[t] = indices[(size_t)b0 * 23 + t];
  __syncthreads();
  if (t < FIN_EPB) {
    int cc = 0;
#pragma unroll
    for (int j = 0; j < 20; ++j) cc += (ind_s[t * 23 + 3 + j] > 0) ? 1 : 0;
    ccs[t] = 1.0f / (float)(cc > 0 ? cc : 1);
  }
  __syncthreads();

  // ---- phase A ----
  {
    // ing1/ing2: 512 f4 slots, 2 per thread
#pragma unroll
    for (int q = 0; q < 2; ++q) {
      const int s = t + q * 256;
      const int e = s >> 6;
      const int half = (s >> 5) & 1;
      const int fg = s & 31;
      const int idx = ind_s[e * 23 + half];
      *(float4*)&ysm[e * 384 + half * 128 + fg * 4] =
          *(const float4*)&x2[(size_t)idx * 128 + fg * 4];
    }
    // ctx: thread owns (e, fg); 20 independent f4 gathers, register sum
    const int e = t >> 5;
    const int fg = t & 31;
    float4 acc = make_float4(0.f, 0.f, 0.f, 0.f);
#pragma unroll
    for (int j = 0; j < 20; ++j) {
      const int cj = ind_s[e * 23 + 3 + j];
      const float4 a = *(const float4*)&x2[(size_t)cj * 128 + fg * 4];
      acc.x += a.x; acc.y += a.y; acc.z += a.z; acc.w += a.w;
    }
    const float sc = ccs[e];
    acc.x *= sc; acc.y *= sc; acc.z *= sc; acc.w *= sc;
    *(float4*)&ysm[e * 384 + 256 + fg * 4] = acc;
  }
  __syncthreads();

  // ---- phase B: layer 1 (384 -> 128), 4 elems per thread ----
  {
    const int f1 = t & 127;
    const int eh = t >> 7;                     // elems eh*4 .. eh*4+3
    float acc[4];
    const float b = bc1[f1];
#pragma unroll
    for (int i = 0; i < 4; ++i) acc[i] = b;
    for (int k = 0; k < 384; k += 4) {
      const float wv0 = Wc1t[(k + 0) * 128 + f1];
      const float wv1 = Wc1t[(k + 1) * 128 + f1];
      const float wv2 = Wc1t[(k + 2) * 128 + f1];
      const float wv3 = Wc1t[(k + 3) * 128 + f1];
#pragma unroll
      for (int i = 0; i < 4; ++i) {
        const float4 yv = *(const float4*)&ysm[(eh * 4 + i) * 384 + k];
        acc[i] += yv.x * wv0 + yv.y * wv1 + yv.z * wv2 + yv.w * wv3;
      }
    }
#pragma unroll
    for (int i = 0; i < 4; ++i)
      h1s[(eh * 4 + i) * 128 + f1] = fmaxf(acc[i], 0.f);
  }
  __syncthreads();

  // ---- phase C: layer 2 (128 -> 64), 2 elems per thread ----
  {
    const int f2 = t & 63;
    const int eg = t >> 6;                     // elems eg*2 .. eg*2+1
    float acc[2];
    const float b = bc2[f2];
#pragma unroll
    for (int i = 0; i < 2; ++i) acc[i] = b;
    for (int k = 0; k < 128; k += 4) {
      const float wv0 = Wc2t[(k + 0) * 64 + f2];
      const float wv1 = Wc2t[(k + 1) * 64 + f2];
      const float wv2 = Wc2t[(k + 2) * 64 + f2];
      const float wv3 = Wc2t[(k + 3) * 64 + f2];
#pragma unroll
      for (int i = 0; i < 2; ++i) {
        const float4 hv = *(const float4*)&h1s[(eg * 2 + i) * 128 + k];
        acc[i] += hv.x * wv0 + hv.y * wv1 + hv.z * wv2 + hv.w * wv3;
      }
    }
#pragma unroll
    for (int i = 0; i < 2; ++i)
      h2s[(eg * 2 + i) * 64 + f2] = fmaxf(acc[i], 0.f);
  }
  __syncthreads();

  // ---- phase D: layer 3 (64 -> 1), 32 lanes per element ----
  {
    const int e = t >> 5;
    const int l = t & 31;
    float p = h2s[e * 64 + l] * Wc3[l] + h2s[e * 64 + l + 32] * Wc3[l + 32];
#pragma unroll
    for (int o = 16; o > 0; o >>= 1) p += __shfl_down(p, o, 32);
    if (l == 0) out[b0 + e] = p + bc3[0];
  }
}

extern "C" void kernel_launch(void* const* d_in, const int* in_sizes, int n_in,
                              void* d_out, int out_size, void* d_ws, size_t ws_size,
                              hipStream_t stream) {
  const int* indices = (const int*)d_in[0];
  const int* src = (const int*)d_in[1];
  const int* dst = (const int*)d_in[2];
  const float* w = (const float*)d_in[3];
  const float* ndata = (const float*)d_in[4];
  const float* W1 = (const float*)d_in[5];
  const float* b1 = (const float*)d_in[6];
  const float* W2 = (const float*)d_in[7];
  const float* b2 = (const float*)d_in[8];
  const float* eps = (const float*)d_in[9];
  const float* Wc1 = (const float*)d_in[10];
  const float* bc1 = (const float*)d_in[11];
  const float* Wc2 = (const float*)d_in[12];
  const float* bc2 = (const float*)d_in[13];
  const float* Wc3 = (const float*)d_in[14];
  const float* bc3 = (const float*)d_in[15];
  float* out = (float*)d_out;

  const int E = in_sizes[1];
  const int N = in_sizes[4] / 128;
  const int B = in_sizes[0] / 23;

  char* ws = (char*)d_ws;
  size_t off = 0;
  auto alloc = [&](size_t bytes) -> char* {
    char* p = ws + off;
    off = (off + bytes + 255) & ~(size_t)255;
    return p;
  };
  const size_t Epad = (size_t)E + 8 * (size_t)N;   // worst-case padded edge count
  int* cnt = (int*)alloc((size_t)N * 4);
  int* prow = (int*)alloc((size_t)(N + 1) * 4);
  int* rank = (int*)alloc((size_t)E * 4);
  int* bsum = (int*)alloc(256 * 4);
  int2* epack = (int2*)alloc(Epad * 8);
  float* x1 = (float*)alloc((size_t)N * 128 * 4);
  float* x2 = (float*)alloc((size_t)N * 128 * 4);
  float* Wt1 = (float*)alloc(16384 * 4);
  float* Wt2 = (float*)alloc(16384 * 4);
  float* Wc1t = (float*)alloc(49152 * 4);
  float* Wc2t = (float*)alloc(8192 * 4);

  hipMemsetAsync(epack, 0, Epad * 8, stream);      // pad slots -> (src=0, w=0)

  const int ninit = (N > 90112) ? N : 90112;
  init_kernel<<<(ninit + 255) / 256, 256, 0, stream>>>(W1, W2, Wc1, Wc2, Wt1, Wt2, Wc1t, Wc2t, cnt, N);
  const int Eh = (E + 1) / 2;
  hist_kernel<<<(Eh + 255) / 256, 256, 0, stream>>>(dst, cnt, rank, E);
  const int nchunk = (N + 2047) / 2048;
  scan1_kernel<<<nchunk, 256, 0, stream>>>(cnt, prow, bsum, N);
  scan2_kernel<<<1, 64, 0, stream>>>(bsum, nchunk);
  scatter_kernel<<<(Eh + 255) / 256, 256, 0, stream>>>(src, dst, w, prow, bsum, rank, epack, E);

  const int nconv = (N + CONV_NPB - 1) / CONV_NPB;
  conv_kernel<<<nconv, 256, 0, stream>>>(ndata, x1, prow, bsum, cnt, epack, Wt1, b1, eps, 0, 1, 0, N, nchunk);
  conv_kernel<<<nconv, 256, 0, stream>>>(x1, x2, prow, bsum, cnt, epack, Wt2, b2, eps, 1, 0, 1, N, nchunk);

  final_kernel<<<B / FIN_EPB, 256, 0, stream>>>(x2, indices, Wc1t, bc1, Wc2t, bc2, Wc3, bc3, out);
}

// Round 11
// 589.145 us; speedup vs baseline: 1.2342x; 1.0144x over previous
//
#include <hip/hip_runtime.h>

// GIN_MLP: 2x GIN conv (N=100000, E=1.6M, H=128) + per-batch context MLP (B=4096).
// Device-built dst-CSR (rank-based atomic-free scatter, 8-aligned padded rows)
// -> fused aggregate+GEMM (R7 laneset-f4 gather, proven 176 us = LLC random-
// access wall: 819 MB of random 512B row reads) -> tiled final MLP. All f32.
// R11: E-pass polish. hist/scatter 4 edges/thread (int4); epack memset dropped
// (scatter zeroes only actual pad slots); 8 dispatches.

#define CONV_NPB 32
#define FIN_EPB 8

// init: weight transposes + cnt zeroing (grid covers max(N, 90112))
__global__ void init_kernel(const float* __restrict__ W1, const float* __restrict__ W2,
                            const float* __restrict__ Wc1, const float* __restrict__ Wc2,
                            float* __restrict__ Wt1, float* __restrict__ Wt2,
                            float* __restrict__ Wc1t, float* __restrict__ Wc2t,
                            int* __restrict__ cnt, int n) {
  int i = blockIdx.x * blockDim.x + threadIdx.x;
  if (i < n) cnt[i] = 0;
  if (i < 16384) {
    int f = i >> 7, k = i & 127;
    Wt1[k * 128 + f] = W1[i];
  } else if (i < 32768) {
    int j = i - 16384; int f = j >> 7, k = j & 127;
    Wt2[k * 128 + f] = W2[j];
  } else if (i < 81920) {
    int j = i - 32768; int f = j / 384, k = j % 384;
    Wc1t[k * 128 + f] = Wc1[j];
  } else if (i < 90112) {
    int j = i - 81920; int f = j >> 7, k = j & 127;
    Wc2t[k * 64 + f] = Wc2[j];
  }
}

// per-dst degree + per-edge arrival rank; 4 edges/thread
__global__ void hist_kernel(const int* __restrict__ dst, int* __restrict__ cnt,
                            int* __restrict__ rank, int E) {
  int e = (blockIdx.x * blockDim.x + threadIdx.x) * 4;
  if (e + 3 < E) {
    const int4 d = *(const int4*)&dst[e];
    int4 r;
    r.x = atomicAdd(&cnt[d.x], 1);
    r.y = atomicAdd(&cnt[d.y], 1);
    r.z = atomicAdd(&cnt[d.z], 1);
    r.w = atomicAdd(&cnt[d.w], 1);
    *(int4*)&rank[e] = r;
  } else {
    for (; e < E; ++e) rank[e] = atomicAdd(&cnt[dst[e]], 1);
  }
}

// per-2048-chunk exclusive scan of PADDED counts (ceil(cnt/8)*8); bsum[b] = chunk total
__global__ void scan1_kernel(const int* __restrict__ cnt, int* __restrict__ prow,
                             int* __restrict__ bsum, int n) {
  __shared__ int smem[256];
  const int t = threadIdx.x;
  const int base = blockIdx.x * 2048 + t * 8;
  int v[8];
  int s = 0;
#pragma unroll
  for (int j = 0; j < 8; ++j) {
    int idx = base + j;
    v[j] = (idx < n) ? ((cnt[idx] + 7) & ~7) : 0;
    s += v[j];
  }
  smem[t] = s;
  __syncthreads();
  for (int off = 1; off < 256; off <<= 1) {
    int add = (t >= off) ? smem[t - off] : 0;
    __syncthreads();
    smem[t] += add;
    __syncthreads();
  }
  int run = smem[t] - s;
  if (t == 255) bsum[blockIdx.x] = smem[255];
#pragma unroll
  for (int j = 0; j < 8; ++j) {
    int idx = base + j;
    if (idx < n) prow[idx] = run;
    run += v[j];
  }
}

// 64-lane shuffle scan (nchunk=49 fits); appends grand total at bsum[nb]
__global__ void scan2_kernel(int* __restrict__ bsum, int nb) {
  const int t = threadIdx.x;
  if (nb <= 64) {
    const int orig = (t < nb) ? bsum[t] : 0;
    int v = orig;
#pragma unroll
    for (int off = 1; off < 64; off <<= 1) {
      int u = __shfl_up(v, off);
      if (t >= off) v += u;
    }
    if (t == nb - 1) bsum[nb] = v;
    if (t < nb) bsum[t] = v - orig;
  } else if (t == 0) {
    int run = 0;
    for (int i = 0; i < nb; ++i) { int v = bsum[i]; bsum[i] = run; run += v; }
    bsum[nb] = run;
  }
}

// atomic-free scatter into padded CSR, 4 edges/thread; threads i<n also zero
// their node's pad slots (replaces the 14.4 MB epack memset; real slots and
// pad slots exactly partition the padded CSR, so no races and full coverage)
__global__ void scatter_kernel(const int* __restrict__ src, const int* __restrict__ dst,
                               const float* __restrict__ w, const int* __restrict__ prow,
                               const int* __restrict__ bsum, const int* __restrict__ rank,
                               const int* __restrict__ cnt,
                               int2* __restrict__ epack, int E, int n) {
  const int i = blockIdx.x * blockDim.x + threadIdx.x;
  int e = i * 4;
  if (e + 3 < E) {
    const int4 d = *(const int4*)&dst[e];
    const int4 s = *(const int4*)&src[e];
    const float4 wv = *(const float4*)&w[e];
    const int4 r = *(const int4*)&rank[e];
    epack[prow[d.x] + bsum[d.x >> 11] + r.x] = make_int2(s.x, __float_as_int(wv.x));
    epack[prow[d.y] + bsum[d.y >> 11] + r.y] = make_int2(s.y, __float_as_int(wv.y));
    epack[prow[d.z] + bsum[d.z >> 11] + r.z] = make_int2(s.z, __float_as_int(wv.z));
    epack[prow[d.w] + bsum[d.w >> 11] + r.w] = make_int2(s.w, __float_as_int(wv.w));
  } else {
    for (; e < E; ++e) {
      const int d = dst[e];
      epack[prow[d] + bsum[d >> 11] + rank[e]] = make_int2(src[e], __float_as_int(w[e]));
    }
  }
  if (i < n) {
    const int c = cnt[i];
    const int start = prow[i] + bsum[i >> 11] + c;
    const int pc = ((c + 7) & ~7) - c;
    for (int j = 0; j < pc; ++j) epack[start + j] = make_int2(0, 0);
  }
}

// Stage 1 (R7, proven): block's 32 rows = contiguous 8-aligned padded edge
// range, split into 8 laneset chunks (multiples of 8). Per 8-edge batch:
// 4 int4 descriptor loads + 8 independent float4 gathers + 32 FMA,
// straight-line; register acc flushes to LDS (permuted, bank=lane) only at row
// transitions. Stage 2: de-permute + (1+eps)x + agg/deg. Stage 3: GEMM.
__launch_bounds__(256, 6)
__global__ void conv_kernel(const float* __restrict__ xin, float* __restrict__ xout,
                            const int* __restrict__ prow, const int* __restrict__ bsum,
                            const int* __restrict__ cnt,
                            const int2* __restrict__ epack,
                            const float* __restrict__ Wt,
                            const float* __restrict__ bias, const float* __restrict__ eps,
                            int epsidx, int dorelu, int zerorow0, int n, int nchunk) {
  __shared__ float xm[CONV_NPB * 128];
  __shared__ int rp_s[CONV_NPB + 1];
  const int t = threadIdx.x;
  const int nb = blockIdx.x * CONV_NPB;
  const float epsv = 1.0f + eps[epsidx];

#pragma unroll
  for (int i = 0; i < 4; ++i)
    *(float4*)&xm[(t + i * 256) * 4] = make_float4(0.f, 0.f, 0.f, 0.f);
  if (t <= CONV_NPB) {
    const int node = nb + t;
    rp_s[t] = (node >= n) ? bsum[nchunk] : (prow[node] + bsum[node >> 11]);
  }
  __syncthreads();

  // ---- stage 1: padded 8-batch laneset-f4 gather ----
  {
    const int L = t >> 5;
    const int lane = t & 31;
    const int f0 = lane * 4;
    const int e0 = rp_s[0], eT = rp_s[CONV_NPB];
    const int nbat = (eT - e0) >> 3;
    const int chunk = (((nbat + 7) >> 3)) << 3;
    const int jb = e0 + L * chunk;
    const int je = min(jb + chunk, eT);
    if (jb < je) {
      const int4* ep4 = (const int4*)epack;
      int r = 0;
      while (rp_s[r + 1] <= jb) ++r;
      float4 acc = make_float4(0.f, 0.f, 0.f, 0.f);
      for (int j = jb; j < je; j += 8) {
        if (rp_s[r + 1] <= j) {
          float* bp = &xm[r * 128 + lane];
          atomicAdd(bp + 0,  acc.x);
          atomicAdd(bp + 32, acc.y);
          atomicAdd(bp + 64, acc.z);
          atomicAdd(bp + 96, acc.w);
          acc = make_float4(0.f, 0.f, 0.f, 0.f);
          do { ++r; } while (rp_s[r + 1] <= j);
        }
        const int h = j >> 1;
        const int4 q0 = ep4[h + 0];
        const int4 q1 = ep4[h + 1];
        const int4 q2 = ep4[h + 2];
        const int4 q3 = ep4[h + 3];
        const float4 a0 = *(const float4*)&xin[(size_t)q0.x * 128 + f0];
        const float4 a1 = *(const float4*)&xin[(size_t)q0.z * 128 + f0];
        const float4 a2 = *(const float4*)&xin[(size_t)q1.x * 128 + f0];
        const float4 a3 = *(const float4*)&xin[(size_t)q1.z * 128 + f0];
        const float4 a4 = *(const float4*)&xin[(size_t)q2.x * 128 + f0];
        const float4 a5 = *(const float4*)&xin[(size_t)q2.z * 128 + f0];
        const float4 a6 = *(const float4*)&xin[(size_t)q3.x * 128 + f0];
        const float4 a7 = *(const float4*)&xin[(size_t)q3.z * 128 + f0];
        const float w0 = __int_as_float(q0.y), w1 = __int_as_float(q0.w);
        const float w2 = __int_as_float(q1.y), w3 = __int_as_float(q1.w);
        const float w4 = __int_as_float(q2.y), w5 = __int_as_float(q2.w);
        const float w6 = __int_as_float(q3.y), w7 = __int_as_float(q3.w);
        acc.x += w0 * a0.x + w1 * a1.x + w2 * a2.x + w3 * a3.x
               + w4 * a4.x + w5 * a5.x + w6 * a6.x + w7 * a7.x;
        acc.y += w0 * a0.y + w1 * a1.y + w2 * a2.y + w3 * a3.y
               + w4 * a4.y + w5 * a5.y + w6 * a6.y + w7 * a7.y;
        acc.z += w0 * a0.z + w1 * a1.z + w2 * a2.z + w3 * a3.z
               + w4 * a4.z + w5 * a5.z + w6 * a6.z + w7 * a7.z;
        acc.w += w0 * a0.w + w1 * a1.w + w2 * a2.w + w3 * a3.w
               + w4 * a4.w + w5 * a5.w + w6 * a6.w + w7 * a7.w;
      }
      float* bp = &xm[r * 128 + lane];
      atomicAdd(bp + 0,  acc.x);
      atomicAdd(bp + 32, acc.y);
      atomicAdd(bp + 64, acc.z);
      atomicAdd(bp + 96, acc.w);
    }
  }
  __syncthreads();

  // ---- stage 2: de-permute + finalize (1+eps)*x + agg/deg ----
  {
    float4 m[4];
#pragma unroll
    for (int q = 0; q < 4; ++q) {
      const int task = t + q * 256;
      const int r = task >> 5;
      const int fg = task & 31;
      m[q].x = xm[r * 128 + fg];
      m[q].y = xm[r * 128 + 32 + fg];
      m[q].z = xm[r * 128 + 64 + fg];
      m[q].w = xm[r * 128 + 96 + fg];
    }
    __syncthreads();
#pragma unroll
    for (int q = 0; q < 4; ++q) {
      const int task = t + q * 256;
      const int r = task >> 5;
      const int fg = task & 31;
      const int f0 = fg * 4;
      const int node = nb + r;
      float4 v = make_float4(0.f, 0.f, 0.f, 0.f);
      if (node < n) {
        const int d = cnt[node];
        const float rdeg = 1.0f / (float)(d > 1 ? d : 1);
        const float4 xv = *(const float4*)&xin[(size_t)node * 128 + f0];
        v.x = epsv * xv.x + m[q].x * rdeg;
        v.y = epsv * xv.y + m[q].y * rdeg;
        v.z = epsv * xv.z + m[q].z * rdeg;
        v.w = epsv * xv.w + m[q].w * rdeg;
      }
      *(float4*)&xm[r * 128 + f0] = v;
    }
  }
  __syncthreads();

  // ---- stage 3: GEMM, thread tile = 4 rows x 4 features ----
  {
    const int fg = t & 31;
    const int rg = t >> 5;
    const int f0 = fg * 4;
    const int r0 = rg * 4;
    float4 acc[4];
#pragma unroll
    for (int r = 0; r < 4; ++r) acc[r] = make_float4(0.f, 0.f, 0.f, 0.f);
    for (int k = 0; k < 128; k += 4) {
      const float4 w0 = *(const float4*)&Wt[(k + 0) * 128 + f0];
      const float4 w1 = *(const float4*)&Wt[(k + 1) * 128 + f0];
      const float4 w2 = *(const float4*)&Wt[(k + 2) * 128 + f0];
      const float4 w3 = *(const float4*)&Wt[(k + 3) * 128 + f0];
#pragma unroll
      for (int r = 0; r < 4; ++r) {
        const float4 xv = *(const float4*)&xm[(r0 + r) * 128 + k];
        acc[r].x += xv.x * w0.x + xv.y * w1.x + xv.z * w2.x + xv.w * w3.x;
        acc[r].y += xv.x * w0.y + xv.y * w1.y + xv.z * w2.y + xv.w * w3.y;
        acc[r].z += xv.x * w0.z + xv.y * w1.z + xv.z * w2.z + xv.w * w3.z;
        acc[r].w += xv.x * w0.w + xv.y * w1.w + xv.z * w2.w + xv.w * w3.w;
      }
    }
    const float4 bv = *(const float4*)&bias[f0];
#pragma unroll
    for (int r = 0; r < 4; ++r) {
      const int node = nb + r0 + r;
      if (node < n) {
        float4 v;
        v.x = acc[r].x + bv.x;
        v.y = acc[r].y + bv.y;
        v.z = acc[r].z + bv.z;
        v.w = acc[r].w + bv.w;
        if (dorelu) {
          v.x = fmaxf(v.x, 0.f); v.y = fmaxf(v.y, 0.f);
          v.z = fmaxf(v.z, 0.f); v.w = fmaxf(v.w, 0.f);
        }
        if (zerorow0 && node == 0) { v.x = 0.f; v.y = 0.f; v.z = 0.f; v.w = 0.f; }
        *(float4*)&xout[(size_t)node * 128 + f0] = v;
      }
    }
  }
}

// Final MLP (R10, proven): 8 elems per 256-thread block (512 blocks).
__launch_bounds__(256, 4)
__global__ void final_kernel(const float* __restrict__ x2, const int* __restrict__ indices,
                             const float* __restrict__ Wc1t, const float* __restrict__ bc1,
                             const float* __restrict__ Wc2t, const float* __restrict__ bc2,
                             const float* __restrict__ Wc3, const float* __restrict__ bc3,
                             float* __restrict__ out) {
  __shared__ float ysm[FIN_EPB * 384];
  __shared__ float h1s[FIN_EPB * 128];
  __shared__ float h2s[FIN_EPB * 64];
  __shared__ int ind_s[FIN_EPB * 23];
  __shared__ float ccs[FIN_EPB];
  const int t = threadIdx.x;
  const int b0 = blockIdx.x * FIN_EPB;

  if (t < FIN_EPB * 23) ind_s[t] = indices[(size_t)b0 * 23 + t];
  __syncthreads();
  if (t < FIN_EPB) {
    int cc = 0;
#pragma unroll
    for (int j = 0; j < 20; ++j) cc += (ind_s[t * 23 + 3 + j] > 0) ? 1 : 0;
    ccs[t] = 1.0f / (float)(cc > 0 ? cc : 1);
  }
  __syncthreads();

  // ---- phase A ----
  {
#pragma unroll
    for (int q = 0; q < 2; ++q) {
      const int s = t + q * 256;
      const int e = s >> 6;
      const int half = (s >> 5) & 1;
      const int fg = s & 31;
      const int idx = ind_s[e * 23 + half];
      *(float4*)&ysm[e * 384 + half * 128 + fg * 4] =
          *(const float4*)&x2[(size_t)idx * 128 + fg * 4];
    }
    const int e = t >> 5;
    const int fg = t & 31;
    float4 acc = make_float4(0.f, 0.f, 0.f, 0.f);
#pragma unroll
    for (int j = 0; j < 20; ++j) {
      const int cj = ind_s[e * 23 + 3 + j];
      const float4 a = *(const float4*)&x2[(size_t)cj * 128 + fg * 4];
      acc.x += a.x; acc.y += a.y; acc.z += a.z; acc.w += a.w;
    }
    const float sc = ccs[e];
    acc.x *= sc; acc.y *= sc; acc.z *= sc; acc.w *= sc;
    *(float4*)&ysm[e * 384 + 256 + fg * 4] = acc;
  }
  __syncthreads();

  // ---- phase B: layer 1 (384 -> 128), 4 elems per thread ----
  {
    const int f1 = t & 127;
    const int eh = t >> 7;
    float acc[4];
    const float b = bc1[f1];
#pragma unroll
    for (int i = 0; i < 4; ++i) acc[i] = b;
    for (int k = 0; k < 384; k += 4) {
      const float wv0 = Wc1t[(k + 0) * 128 + f1];
      const float wv1 = Wc1t[(k + 1) * 128 + f1];
      const float wv2 = Wc1t[(k + 2) * 128 + f1];
      const float wv3 = Wc1t[(k + 3) * 128 + f1];
#pragma unroll
      for (int i = 0; i < 4; ++i) {
        const float4 yv = *(const float4*)&ysm[(eh * 4 + i) * 384 + k];
        acc[i] += yv.x * wv0 + yv.y * wv1 + yv.z * wv2 + yv.w * wv3;
      }
    }
#pragma unroll
    for (int i = 0; i < 4; ++i)
      h1s[(eh * 4 + i) * 128 + f1] = fmaxf(acc[i], 0.f);
  }
  __syncthreads();

  // ---- phase C: layer 2 (128 -> 64), 2 elems per thread ----
  {
    const int f2 = t & 63;
    const int eg = t >> 6;
    float acc[2];
    const float b = bc2[f2];
#pragma unroll
    for (int i = 0; i < 2; ++i) acc[i] = b;
    for (int k = 0; k < 128; k += 4) {
      const float wv0 = Wc2t[(k + 0) * 64 + f2];
      const float wv1 = Wc2t[(k + 1) * 64 + f2];
      const float wv2 = Wc2t[(k + 2) * 64 + f2];
      const float wv3 = Wc2t[(k + 3) * 64 + f2];
#pragma unroll
      for (int i = 0; i < 2; ++i) {
        const float4 hv = *(const float4*)&h1s[(eg * 2 + i) * 128 + k];
        acc[i] += hv.x * wv0 + hv.y * wv1 + hv.z * wv2 + hv.w * wv3;
      }
    }
#pragma unroll
    for (int i = 0; i < 2; ++i)
      h2s[(eg * 2 + i) * 64 + f2] = fmaxf(acc[i], 0.f);
  }
  __syncthreads();

  // ---- phase D: layer 3 (64 -> 1), 32 lanes per element ----
  {
    const int e = t >> 5;
    const int l = t & 31;
    float p = h2s[e * 64 + l] * Wc3[l] + h2s[e * 64 + l + 32] * Wc3[l + 32];
#pragma unroll
    for (int o = 16; o > 0; o >>= 1) p += __shfl_down(p, o, 32);
    if (l == 0) out[b0 + e] = p + bc3[0];
  }
}

extern "C" void kernel_launch(void* const* d_in, const int* in_sizes, int n_in,
                              void* d_out, int out_size, void* d_ws, size_t ws_size,
                              hipStream_t stream) {
  const int* indices = (const int*)d_in[0];
  const int* src = (const int*)d_in[1];
  const int* dst = (const int*)d_in[2];
  const float* w = (const float*)d_in[3];
  const float* ndata = (const float*)d_in[4];
  const float* W1 = (const float*)d_in[5];
  const float* b1 = (const float*)d_in[6];
  const float* W2 = (const float*)d_in[7];
  const float* b2 = (const float*)d_in[8];
  const float* eps = (const float*)d_in[9];
  const float* Wc1 = (const float*)d_in[10];
  const float* bc1 = (const float*)d_in[11];
  const float* Wc2 = (const float*)d_in[12];
  const float* bc2 = (const float*)d_in[13];
  const float* Wc3 = (const float*)d_in[14];
  const float* bc3 = (const float*)d_in[15];
  float* out = (float*)d_out;

  const int E = in_sizes[1];
  const int N = in_sizes[4] / 128;
  const int B = in_sizes[0] / 23;

  char* ws = (char*)d_ws;
  size_t off = 0;
  auto alloc = [&](size_t bytes) -> char* {
    char* p = ws + off;
    off = (off + bytes + 255) & ~(size_t)255;
    return p;
  };
  const size_t Epad = (size_t)E + 8 * (size_t)N;   // worst-case padded edge count
  int* cnt = (int*)alloc((size_t)N * 4);
  int* prow = (int*)alloc((size_t)(N + 1) * 4);
  int* rank = (int*)alloc((size_t)E * 4);
  int* bsum = (int*)alloc(256 * 4);
  int2* epack = (int2*)alloc(Epad * 8);
  float* x1 = (float*)alloc((size_t)N * 128 * 4);
  float* x2 = (float*)alloc((size_t)N * 128 * 4);
  float* Wt1 = (float*)alloc(16384 * 4);
  float* Wt2 = (float*)alloc(16384 * 4);
  float* Wc1t = (float*)alloc(49152 * 4);
  float* Wc2t = (float*)alloc(8192 * 4);

  const int ninit = (N > 90112) ? N : 90112;
  init_kernel<<<(ninit + 255) / 256, 256, 0, stream>>>(W1, W2, Wc1, Wc2, Wt1, Wt2, Wc1t, Wc2t, cnt, N);
  const int Eq = (E + 3) / 4;
  hist_kernel<<<(Eq + 255) / 256, 256, 0, stream>>>(dst, cnt, rank, E);
  const int nchunk = (N + 2047) / 2048;
  scan1_kernel<<<nchunk, 256, 0, stream>>>(cnt, prow, bsum, N);
  scan2_kernel<<<1, 64, 0, stream>>>(bsum, nchunk);
  const int nsc = (Eq > N) ? Eq : N;
  scatter_kernel<<<(nsc + 255) / 256, 256, 0, stream>>>(src, dst, w, prow, bsum, rank, cnt, epack, E, N);

  const int nconv = (N + CONV_NPB - 1) / CONV_NPB;
  conv_kernel<<<nconv, 256, 0, stream>>>(ndata, x1, prow, bsum, cnt, epack, Wt1, b1, eps, 0, 1, 0, N, nchunk);
  conv_kernel<<<nconv, 256, 0, stream>>>(x1, x2, prow, bsum, cnt, epack, Wt2, b2, eps, 1, 0, 1, N, nchunk);

  final_kernel<<<B / FIN_EPB, 256, 0, stream>>>(x2, indices, Wc1t, bc1, Wc2t, bc2, Wc3, bc3, out);
}